// Round 4
// baseline (946.213 us; speedup 1.0000x reference)
//
#include <hip/hip_runtime.h>
#include <hip/hip_bf16.h>

typedef unsigned short u16;
typedef unsigned int   u32;
typedef short   bf16x8 __attribute__((ext_vector_type(8)));  // bf16 carried as i16 (guide-verified form)
typedef float   f32x4  __attribute__((ext_vector_type(4)));

__device__ __forceinline__ u32 f2bf(float f) {
    u32 u = __builtin_bit_cast(u32, f);
    return (u + 0x7FFFu + ((u >> 16) & 1u)) >> 16;   // RNE
}

// ---------------------------------------------------------------------------
// Kernel Z: zero the offset/mask accumulator (ws is poisoned 0xAA each call)
// ---------------------------------------------------------------------------
__global__ void zerok(float* __restrict__ p) {
    p[blockIdx.x * 256 + threadIdx.x] = 0.f;     // 27*16384 exact
}

// ---------------------------------------------------------------------------
// Kernel 0a: repack conv weights (f32) -> fp32 wprep[r][28]
// r = c*9 + tap (2304 rows), cols 0..17 = w_off, 18..26 = w_mod, 27 = 0 pad.
// ---------------------------------------------------------------------------
__global__ void kprep(const float* __restrict__ woff, const float* __restrict__ wmod,
                      float* __restrict__ wprep) {
    int i = blockIdx.x * 256 + threadIdx.x;
    if (i >= 2304 * 28) return;
    int r = i / 28, oc = i - r * 28;
    float v = 0.f;
    if (oc < 18)      v = woff[oc * 2304 + r];
    else if (oc < 27) v = wmod[(oc - 18) * 2304 + r];
    wprep[i] = v;
}

// ---------------------------------------------------------------------------
// Kernel 0b: convert w_reg f32 -> bf16, layout [o][r] (r = c*9+tap), 589824 elts
// ---------------------------------------------------------------------------
__global__ void kwreg(const float* __restrict__ wreg, u16* __restrict__ wregb) {
    int i = blockIdx.x * 256 + threadIdx.x;      // 2304 blocks exact
    wregb[i] = (u16)f2bf(wreg[i]);
}

// ---------------------------------------------------------------------------
// Kernel 1: offset/mask conv. Thread = pixel n, c-quarter q (64 ch).
// Partial sums combined via fp32 atomicAdd into offsum[oc][n] (pre-zeroed).
// ---------------------------------------------------------------------------
__global__ __launch_bounds__(256) void koffmask(const float* __restrict__ x,
                                                const float* __restrict__ wprep,
                                                float* __restrict__ offsum) {
    int nb = blockIdx.x >> 2, q = blockIdx.x & 3;
    int n = nb * 256 + threadIdx.x;
    int b = n >> 12, hw = n & 4095, h = hw >> 6, w = hw & 63;

    int   offs[9];
    float valid[9];
#pragma unroll
    for (int ky = 0; ky < 3; ky++)
#pragma unroll
        for (int kx = 0; kx < 3; kx++) {
            int y = h - 1 + ky, xx = w - 1 + kx;
            bool v = (y >= 0) && (y < 64) && (xx >= 0) && (xx < 64);
            int yc = min(max(y, 0), 63), xc = min(max(xx, 0), 63);
            offs[ky * 3 + kx] = yc * 64 + xc;
            valid[ky * 3 + kx] = v ? 1.f : 0.f;
        }

    float acc[28];
#pragma unroll
    for (int j = 0; j < 28; j++) acc[j] = 0.f;

    const float* xb = x + (long)(b * 256 + q * 64) * 4096;
    const float4* wp = (const float4*)wprep;
    for (int c = 0; c < 64; c++) {
        const float* xc = xb + c * 4096;
        float xv[9];
#pragma unroll
        for (int t = 0; t < 9; t++) xv[t] = xc[offs[t]] * valid[t];
        int r0 = (q * 64 + c) * 9;
#pragma unroll
        for (int t = 0; t < 9; t++) {
#pragma unroll
            for (int j = 0; j < 7; j++) {
                float4 wv = wp[(r0 + t) * 7 + j];
                acc[j * 4 + 0] += xv[t] * wv.x;
                acc[j * 4 + 1] += xv[t] * wv.y;
                acc[j * 4 + 2] += xv[t] * wv.z;
                acc[j * 4 + 3] += xv[t] * wv.w;
            }
        }
    }
#pragma unroll
    for (int oc = 0; oc < 27; oc++) atomicAdd(&offsum[(oc << 14) + n], acc[oc]);
}

// ---------------------------------------------------------------------------
// Kernel 1b: bias (+2*sigmoid for mask) -> off_final
// off_final[3k+0]=dy_k, [3k+1]=dx_k, [3k+2]=mask_k  (each [16384] fp32)
// ---------------------------------------------------------------------------
__global__ void kfin(const float* __restrict__ offsum, const float* __restrict__ boff,
                     const float* __restrict__ bmod, float* __restrict__ offf) {
    int i = blockIdx.x * 256 + threadIdx.x;     // 27 * 16384 exact
    int oc = i >> 14, n = i & 16383;
    float s = offsum[(oc << 14) + n];
    int ch; float v;
    if (oc < 18) {
        v = s + boff[oc];
        ch = 3 * (oc >> 1) + (oc & 1);          // even ch -> dy, odd -> dx
    } else {
        float t = s + bmod[oc - 18];
        v = 2.f / (1.f + __expf(-t));
        ch = 3 * (oc - 18) + 2;
    }
    offf[(ch << 14) + n] = v;
}

// ---------------------------------------------------------------------------
// Kernel 2: deformable bilinear sampling for one 2048-pixel chunk ->
// pre-fragmented samp[rb][nloc][8] bf16, rb = r>>3, r = c*9+k.
// ---------------------------------------------------------------------------
__global__ __launch_bounds__(256) void ksamp(const float* __restrict__ x,
                                             const float* __restrict__ offf,
                                             u16* __restrict__ samp, int n0base) {
    int nl = threadIdx.x & 63, cg = threadIdx.x >> 6;
    int nb = blockIdx.x >> 1;
    int cq = ((blockIdx.x & 1) << 2) | cg;      // 0..7, 32 channels each
    int nloc = nb * 64 + nl;                    // 0..2047
    int n = n0base + nloc;
    int b = n >> 12, hw = n & 4095, h = hw >> 6, w = hw & 63;

    int   o00[9], o01[9], o10[9], o11[9];
    float w00[9], w01[9], w10[9], w11[9];
#pragma unroll
    for (int k = 0; k < 9; k++) {
        float dy = offf[((3 * k + 0) << 14) + n];
        float dx = offf[((3 * k + 1) << 14) + n];
        float m  = offf[((3 * k + 2) << 14) + n];
        float py = (float)(h - 1 + (k / 3)) + dy;
        float px = (float)(w - 1 + (k % 3)) + dx;
        float y0f = floorf(py), x0f = floorf(px);
        float wy = py - y0f, wx = px - x0f;
        int iy0 = (int)y0f, ix0 = (int)x0f;
        int iy1 = iy0 + 1, ix1 = ix0 + 1;
        bool vy0 = (unsigned)iy0 < 64u, vy1 = (unsigned)iy1 < 64u;
        bool vx0 = (unsigned)ix0 < 64u, vx1 = (unsigned)ix1 < 64u;
        int cy0 = min(max(iy0, 0), 63), cy1 = min(max(iy1, 0), 63);
        int cx0 = min(max(ix0, 0), 63), cx1 = min(max(ix1, 0), 63);
        o00[k] = cy0 * 64 + cx0; o01[k] = cy0 * 64 + cx1;
        o10[k] = cy1 * 64 + cx0; o11[k] = cy1 * 64 + cx1;
        float a = 1.f - wy, bbw = 1.f - wx;
        w00[k] = (vy0 && vx0) ? a  * bbw * m : 0.f;
        w01[k] = (vy0 && vx1) ? a  * wx  * m : 0.f;
        w10[k] = (vy1 && vx0) ? wy * bbw * m : 0.f;
        w11[k] = (vy1 && vx1) ? wy * wx  * m : 0.f;
    }

    const float* xb = x + (long)(b * 256 + cq * 32) * 4096;
    u32 words[36];
    for (int c8 = 0; c8 < 4; c8++) {
        const float* xc8 = xb + c8 * 8 * 4096;
#pragma unroll
        for (int cc = 0; cc < 8; cc++) {
            const float* xc = xc8 + cc * 4096;
#pragma unroll
            for (int k = 0; k < 9; k++) {
                float v = w00[k] * xc[o00[k]] + w01[k] * xc[o01[k]] +
                          w10[k] * xc[o10[k]] + w11[k] * xc[o11[k]];
                int e = cc * 9 + k;
                u32 bv = f2bf(v);
                if (e & 1) words[e >> 1] |= bv << 16;
                else       words[e >> 1]  = bv;
            }
        }
        int rb0 = cq * 36 + c8 * 9;
#pragma unroll
        for (int o = 0; o < 9; o++) {
            uint4 pk = make_uint4(words[o * 4 + 0], words[o * 4 + 1],
                                  words[o * 4 + 2], words[o * 4 + 3]);
            *(uint4*)(samp + ((long)(rb0 + o) * 2048 + nloc) * 8) = pk;
        }
    }
}

// ---------------------------------------------------------------------------
// Kernel 3: GEMM for one 2048-pixel chunk.
// out[o][n] = relu(BN( sum_r wregb[o][r] * samp[r][nloc] ))
// 128x128 tile, BK=64, 4 waves x (4x4) mfma 16x16x32 bf16, fp32 acc.
// ---------------------------------------------------------------------------
__global__ __launch_bounds__(256) void kgemm(const u16* __restrict__ wregb,
                                             const u16* __restrict__ samp,
                                             const float* __restrict__ gamma,
                                             const float* __restrict__ beta,
                                             const float* __restrict__ rmean,
                                             const float* __restrict__ rvar,
                                             float* __restrict__ out, int n0base) {
    __shared__ u16 Al[128 * 72];   // rows o, 64 k + 8 pad (144B row, 16B aligned)
    __shared__ u16 Bl[128 * 72];   // rows n, 64 k + 8 pad
    int tid = threadIdx.x;
    int mt = blockIdx.x >> 4, ntl = blockIdx.x & 15;
    int o0 = mt * 128;
    int nloc0 = ntl * 128;                       // local within chunk
    int n0 = n0base + nloc0;                     // global pixel base
    int lane = tid & 63, wv = tid >> 6;
    int wo = (wv >> 1) * 64, wn = (wv & 1) * 64;
    int col = lane & 15, quad = lane >> 4;

    f32x4 acc[4][4];
#pragma unroll
    for (int i = 0; i < 4; i++)
#pragma unroll
        for (int j = 0; j < 4; j++) acc[i][j] = (f32x4){0.f, 0.f, 0.f, 0.f};

    for (int kt = 0; kt < 36; kt++) {
        int r0 = kt * 64;
        // stage A: 128 rows x 64 k, thread loads 4x16B (8 lanes/row, coalesced)
#pragma unroll
        for (int i = 0; i < 4; i++) {
            int cidx = tid + i * 256;
            int o = cidx >> 3, qq = cidx & 7;
            *(uint4*)&Al[o * 72 + qq * 8] =
                *(const uint4*)(wregb + (long)(o0 + o) * 2304 + r0 + qq * 8);
        }
        // stage B: 8 rb-rows x 128 n, fully coalesced 16B/lane
        int rb0 = r0 >> 3;
#pragma unroll
        for (int i = 0; i < 4; i++) {
            int cidx = tid + i * 256;
            int rbl = cidx >> 7, nl2 = cidx & 127;
            *(uint4*)&Bl[nl2 * 72 + rbl * 8] =
                *(const uint4*)(samp + ((long)(rb0 + rbl) * 2048 + nloc0 + nl2) * 8);
        }
        __syncthreads();
#pragma unroll
        for (int ks = 0; ks < 2; ks++) {
            bf16x8 af[4], bfr[4];
#pragma unroll
            for (int i = 0; i < 4; i++)
                af[i] = *(const bf16x8*)&Al[(wo + i * 16 + col) * 72 + ks * 32 + quad * 8];
#pragma unroll
            for (int j = 0; j < 4; j++)
                bfr[j] = *(const bf16x8*)&Bl[(wn + j * 16 + col) * 72 + ks * 32 + quad * 8];
#pragma unroll
            for (int i = 0; i < 4; i++)
#pragma unroll
                for (int j = 0; j < 4; j++)
                    acc[i][j] = __builtin_amdgcn_mfma_f32_16x16x32_bf16(
                        af[i], bfr[j], acc[i][j], 0, 0, 0);
        }
        __syncthreads();
    }

    // epilogue: BN + ReLU, D layout: row(o) = quad*4+reg, col(n) = lane&15
#pragma unroll
    for (int i = 0; i < 4; i++) {
        int ob = o0 + wo + i * 16 + quad * 4;
        float inv[4], add[4];
#pragma unroll
        for (int r = 0; r < 4; r++) {
            int o = ob + r;
            float iv = gamma[o] * rsqrtf(rvar[o] + 1e-5f);
            inv[r] = iv; add[r] = beta[o] - rmean[o] * iv;
        }
#pragma unroll
        for (int j = 0; j < 4; j++) {
            int n_g = n0 + wn + j * 16 + col;
            int bb = n_g >> 12, hw = n_g & 4095;
            float* op = out + ((long)bb << 20) + hw;
#pragma unroll
            for (int r = 0; r < 4; r++) {
                float v = acc[i][j][r] * inv[r] + add[r];
                v = fmaxf(v, 0.f);
                op[(long)(ob + r) << 12] = v;
            }
        }
    }
}

// ---------------------------------------------------------------------------
extern "C" void kernel_launch(void* const* d_in, const int* in_sizes, int n_in,
                              void* d_out, int out_size, void* d_ws, size_t ws_size,
                              hipStream_t stream) {
    const float* x     = (const float*)d_in[0];
    const float* woff  = (const float*)d_in[1];
    const float* boff  = (const float*)d_in[2];
    const float* wmod  = (const float*)d_in[3];
    const float* bmod  = (const float*)d_in[4];
    const float* wreg  = (const float*)d_in[5];
    const float* gamma = (const float*)d_in[6];
    const float* beta  = (const float*)d_in[7];
    const float* rmean = (const float*)d_in[8];
    const float* rvar  = (const float*)d_in[9];
    float* out = (float*)d_out;

    char* ws = (char*)d_ws;
    // ws map (total ~15.2 MB):
    //   [0x000000, 0x03F000) wprep   fp32  258 KB
    //   [0x060000, 0x210000) offsum  fp32  1.77 MB (zeroed each call)
    //   [0x260000, 0x410000) offf    fp32  1.77 MB
    //   [0x410000, 0x531000) wregb   bf16  1.18 MB
    //   [0x540000, 0xE80000) samp    bf16  9.44 MB (2304 x 2048 per chunk)
    float* wprep  = (float*)(ws);
    float* offsum = (float*)(ws + 0x60000u);
    float* offf   = (float*)(ws + 0x260000u);
    u16*   wregb  = (u16*)(ws + 0x410000u);
    u16*   samp   = (u16*)(ws + 0x540000u);

    zerok   <<<1728, 256, 0, stream>>>(offsum);
    kprep   <<<252,  256, 0, stream>>>(woff, wmod, wprep);
    kwreg   <<<2304, 256, 0, stream>>>(wreg, wregb);
    koffmask<<<256,  256, 0, stream>>>(x, wprep, offsum);
    kfin    <<<1728, 256, 0, stream>>>(offsum, boff, bmod, offf);
    for (int c = 0; c < 8; c++) {
        ksamp<<<64, 256, 0, stream>>>(x, offf, samp, c * 2048);
        kgemm<<<32, 256, 0, stream>>>(wregb, samp, gamma, beta, rmean, rvar,
                                      out, c * 2048);
    }
}

// Round 5
// 363.299 us; speedup vs baseline: 2.6045x; 2.6045x over previous
//
#include <hip/hip_runtime.h>
#include <hip/hip_bf16.h>

typedef unsigned short u16;
typedef unsigned int   u32;
typedef short   bf16x8 __attribute__((ext_vector_type(8)));  // bf16 carried as i16
typedef float   f32x4  __attribute__((ext_vector_type(4)));

__device__ __forceinline__ u32 f2bf(float f) {
    u32 u = __builtin_bit_cast(u32, f);
    return (u + 0x7FFFu + ((u >> 16) & 1u)) >> 16;   // RNE
}

// ---------------------------------------------------------------------------
// Kernel Z: zero the offset/mask accumulator (ws is poisoned 0xAA each call)
// ---------------------------------------------------------------------------
__global__ void zerok(float* __restrict__ p) {
    p[blockIdx.x * 256 + threadIdx.x] = 0.f;     // 27*16384 exact
}

// ---------------------------------------------------------------------------
// Kernel 0a: repack conv weights (f32) -> fp32 wprep[r][28]
// r = c*9 + tap (2304 rows), cols 0..17 = w_off, 18..26 = w_mod, 27 = 0 pad.
// ---------------------------------------------------------------------------
__global__ void kprep(const float* __restrict__ woff, const float* __restrict__ wmod,
                      float* __restrict__ wprep) {
    int i = blockIdx.x * 256 + threadIdx.x;
    if (i >= 2304 * 28) return;
    int r = i / 28, oc = i - r * 28;
    float v = 0.f;
    if (oc < 18)      v = woff[oc * 2304 + r];
    else if (oc < 27) v = wmod[(oc - 18) * 2304 + r];
    wprep[i] = v;
}

// ---------------------------------------------------------------------------
// Kernel 0b: convert w_reg f32 -> bf16, layout [o][r] (r = c*9+tap), 589824 elts
// ---------------------------------------------------------------------------
__global__ void kwreg(const float* __restrict__ wreg, u16* __restrict__ wregb) {
    int i = blockIdx.x * 256 + threadIdx.x;      // 2304 blocks exact
    wregb[i] = (u16)f2bf(wreg[i]);
}

// ---------------------------------------------------------------------------
// Kernel 1: offset/mask conv. Block = (256-pixel band: 4 rows of one image,
// c-quarter q of 64 ch). x rows staged in LDS per channel with reg prefetch.
// Partial sums combined via fp32 atomicAdd into offsum[oc][n] (pre-zeroed).
// ---------------------------------------------------------------------------
__global__ __launch_bounds__(256) void koffmask(const float* __restrict__ x,
                                                const float* __restrict__ wprep,
                                                float* __restrict__ offsum) {
    __shared__ float xs[6 * 64];                 // rows h0-1 .. h0+4
    int tid = threadIdx.x;
    int nb = blockIdx.x >> 2, q = blockIdx.x & 3;
    int n = nb * 256 + tid;
    int b = nb >> 4;
    int h0 = (nb & 15) << 2;                     // first row of the band
    int lr = tid >> 6, w = tid & 63;
    int h = h0 + lr;

    float vy[3], vx[3]; int xcc[3];
#pragma unroll
    for (int k = 0; k < 3; k++) {
        int y = h - 1 + k;
        vy[k] = (y >= 0 && y < 64) ? 1.f : 0.f;
        int xx = w - 1 + k;
        vx[k] = (xx >= 0 && xx < 64) ? 1.f : 0.f;
        xcc[k] = min(max(xx, 0), 63);
    }
    float valid[9];
#pragma unroll
    for (int t = 0; t < 9; t++) valid[t] = vy[t / 3] * vx[t % 3];

    // staging addresses: element i -> row (i>>6) (global y = h0-1+i>>6, clamped
    // for address safety; valid-mask zeroes the contribution), col i&63
    const float* xb = x + (long)(b * 256 + q * 64) * 4096;
    int i0 = tid, i1 = tid + 256;
    int yc0 = min(max(h0 - 1 + (i0 >> 6), 0), 63);
    int yc1 = min(max(h0 - 1 + (i1 >> 6), 0), 63);
    long a0 = (long)yc0 * 64 + (i0 & 63);
    long a1 = (long)yc1 * 64 + (i1 & 63);
    bool has1 = tid < 128;

    float p0 = xb[a0];
    float p1 = has1 ? xb[a1] : 0.f;

    float acc[28];
#pragma unroll
    for (int j = 0; j < 28; j++) acc[j] = 0.f;

    const float4* wp = (const float4*)wprep;
    for (int c = 0; c < 64; c++) {
        __syncthreads();
        xs[i0] = p0;
        if (has1) xs[i1] = p1;
        __syncthreads();
        if (c < 63) {                            // prefetch next channel
            p0 = xb[(c + 1) * 4096 + a0];
            if (has1) p1 = xb[(c + 1) * 4096 + a1];
        }
        int r0 = (q * 64 + c) * 9;
#pragma unroll
        for (int t = 0; t < 9; t++) {
            float xv = xs[(lr + t / 3) * 64 + xcc[t % 3]] * valid[t];
#pragma unroll
            for (int j = 0; j < 7; j++) {
                float4 wv = wp[(r0 + t) * 7 + j];
                acc[j * 4 + 0] += xv * wv.x;
                acc[j * 4 + 1] += xv * wv.y;
                acc[j * 4 + 2] += xv * wv.z;
                acc[j * 4 + 3] += xv * wv.w;
            }
        }
    }
#pragma unroll
    for (int oc = 0; oc < 27; oc++) atomicAdd(&offsum[(oc << 14) + n], acc[oc]);
}

// ---------------------------------------------------------------------------
// Kernel 1b: bias (+2*sigmoid for mask) -> off_final
// off_final[3k+0]=dy_k, [3k+1]=dx_k, [3k+2]=mask_k  (each [16384] fp32)
// ---------------------------------------------------------------------------
__global__ void kfin(const float* __restrict__ offsum, const float* __restrict__ boff,
                     const float* __restrict__ bmod, float* __restrict__ offf) {
    int i = blockIdx.x * 256 + threadIdx.x;     // 27 * 16384 exact
    int oc = i >> 14, n = i & 16383;
    float s = offsum[(oc << 14) + n];
    int ch; float v;
    if (oc < 18) {
        v = s + boff[oc];
        ch = 3 * (oc >> 1) + (oc & 1);          // even ch -> dy, odd -> dx
    } else {
        float t = s + bmod[oc - 18];
        v = 2.f / (1.f + __expf(-t));
        ch = 3 * (oc - 18) + 2;
    }
    offf[(ch << 14) + n] = v;
}

// ---------------------------------------------------------------------------
// Kernel 2: deformable bilinear sampling for one NL-pixel chunk ->
// pre-fragmented samp[rb][nloc][8] bf16, rb = r>>3, r = c*9+k.
// grid = dim3(NL/64, 2), block 256 (64 pixels x 4 c-groups of 32).
// ---------------------------------------------------------------------------
__global__ __launch_bounds__(256) void ksamp(const float* __restrict__ x,
                                             const float* __restrict__ offf,
                                             u16* __restrict__ samp,
                                             int n0base, int NL) {
    int nl = threadIdx.x & 63, cg = threadIdx.x >> 6;
    int nb = blockIdx.x;
    int cq = (blockIdx.y << 2) | cg;            // 0..7, 32 channels each
    int nloc = nb * 64 + nl;                    // 0..NL-1
    int n = n0base + nloc;
    int b = n >> 12, hw = n & 4095, h = hw >> 6, w = hw & 63;

    int   o00[9], o01[9], o10[9], o11[9];
    float w00[9], w01[9], w10[9], w11[9];
#pragma unroll
    for (int k = 0; k < 9; k++) {
        float dy = offf[((3 * k + 0) << 14) + n];
        float dx = offf[((3 * k + 1) << 14) + n];
        float m  = offf[((3 * k + 2) << 14) + n];
        float py = (float)(h - 1 + (k / 3)) + dy;
        float px = (float)(w - 1 + (k % 3)) + dx;
        float y0f = floorf(py), x0f = floorf(px);
        float wy = py - y0f, wx = px - x0f;
        int iy0 = (int)y0f, ix0 = (int)x0f;
        int iy1 = iy0 + 1, ix1 = ix0 + 1;
        bool vy0 = (unsigned)iy0 < 64u, vy1 = (unsigned)iy1 < 64u;
        bool vx0 = (unsigned)ix0 < 64u, vx1 = (unsigned)ix1 < 64u;
        int cy0 = min(max(iy0, 0), 63), cy1 = min(max(iy1, 0), 63);
        int cx0 = min(max(ix0, 0), 63), cx1 = min(max(ix1, 0), 63);
        o00[k] = cy0 * 64 + cx0; o01[k] = cy0 * 64 + cx1;
        o10[k] = cy1 * 64 + cx0; o11[k] = cy1 * 64 + cx1;
        float a = 1.f - wy, bbw = 1.f - wx;
        w00[k] = (vy0 && vx0) ? a  * bbw * m : 0.f;
        w01[k] = (vy0 && vx1) ? a  * wx  * m : 0.f;
        w10[k] = (vy1 && vx0) ? wy * bbw * m : 0.f;
        w11[k] = (vy1 && vx1) ? wy * wx  * m : 0.f;
    }

    const float* xb = x + (long)(b * 256 + cq * 32) * 4096;
    u32 words[36];
    for (int c8 = 0; c8 < 4; c8++) {
        const float* xc8 = xb + c8 * 8 * 4096;
#pragma unroll
        for (int cc = 0; cc < 8; cc++) {
            const float* xc = xc8 + cc * 4096;
#pragma unroll
            for (int k = 0; k < 9; k++) {
                float v = w00[k] * xc[o00[k]] + w01[k] * xc[o01[k]] +
                          w10[k] * xc[o10[k]] + w11[k] * xc[o11[k]];
                int e = cc * 9 + k;
                u32 bv = f2bf(v);
                if (e & 1) words[e >> 1] |= bv << 16;
                else       words[e >> 1]  = bv;
            }
        }
        int rb0 = cq * 36 + c8 * 9;
#pragma unroll
        for (int o = 0; o < 9; o++) {
            uint4 pk = make_uint4(words[o * 4 + 0], words[o * 4 + 1],
                                  words[o * 4 + 2], words[o * 4 + 3]);
            *(uint4*)(samp + ((long)(rb0 + o) * NL + nloc) * 8) = pk;
        }
    }
}

// ---------------------------------------------------------------------------
// Kernel 3: GEMM for one NL-pixel chunk.
// out[o][n] = relu(BN( sum_r wregb[o][r] * samp[r][nloc] ))
// grid = dim3(NL/128, 2). 128x128 tile, BK=64, 4 waves x (4x4) mfma.
// ---------------------------------------------------------------------------
__global__ __launch_bounds__(256) void kgemm(const u16* __restrict__ wregb,
                                             const u16* __restrict__ samp,
                                             const float* __restrict__ gamma,
                                             const float* __restrict__ beta,
                                             const float* __restrict__ rmean,
                                             const float* __restrict__ rvar,
                                             float* __restrict__ out,
                                             int n0base, int NL) {
    __shared__ u16 Al[128 * 72];   // rows o, 64 k + 8 pad
    __shared__ u16 Bl[128 * 72];   // rows n, 64 k + 8 pad
    int tid = threadIdx.x;
    int mt = blockIdx.y, ntl = blockIdx.x;
    int o0 = mt * 128;
    int nloc0 = ntl * 128;
    int n0 = n0base + nloc0;
    int lane = tid & 63, wv = tid >> 6;
    int wo = (wv >> 1) * 64, wn = (wv & 1) * 64;
    int col = lane & 15, quad = lane >> 4;

    f32x4 acc[4][4];
#pragma unroll
    for (int i = 0; i < 4; i++)
#pragma unroll
        for (int j = 0; j < 4; j++) acc[i][j] = (f32x4){0.f, 0.f, 0.f, 0.f};

    for (int kt = 0; kt < 36; kt++) {
        int r0 = kt * 64;
#pragma unroll
        for (int i = 0; i < 4; i++) {
            int cidx = tid + i * 256;
            int o = cidx >> 3, qq = cidx & 7;
            *(uint4*)&Al[o * 72 + qq * 8] =
                *(const uint4*)(wregb + (long)(o0 + o) * 2304 + r0 + qq * 8);
        }
        int rb0 = r0 >> 3;
#pragma unroll
        for (int i = 0; i < 4; i++) {
            int cidx = tid + i * 256;
            int rbl = cidx >> 7, nl2 = cidx & 127;
            *(uint4*)&Bl[nl2 * 72 + rbl * 8] =
                *(const uint4*)(samp + ((long)(rb0 + rbl) * NL + nloc0 + nl2) * 8);
        }
        __syncthreads();
#pragma unroll
        for (int ks = 0; ks < 2; ks++) {
            bf16x8 af[4], bfr[4];
#pragma unroll
            for (int i = 0; i < 4; i++)
                af[i] = *(const bf16x8*)&Al[(wo + i * 16 + col) * 72 + ks * 32 + quad * 8];
#pragma unroll
            for (int j = 0; j < 4; j++)
                bfr[j] = *(const bf16x8*)&Bl[(wn + j * 16 + col) * 72 + ks * 32 + quad * 8];
#pragma unroll
            for (int i = 0; i < 4; i++)
#pragma unroll
                for (int j = 0; j < 4; j++)
                    acc[i][j] = __builtin_amdgcn_mfma_f32_16x16x32_bf16(
                        af[i], bfr[j], acc[i][j], 0, 0, 0);
        }
        __syncthreads();
    }

    // epilogue: BN + ReLU, D layout: row(o) = quad*4+reg, col(n) = lane&15
#pragma unroll
    for (int i = 0; i < 4; i++) {
        int ob = o0 + wo + i * 16 + quad * 4;
        float inv[4], add[4];
#pragma unroll
        for (int r = 0; r < 4; r++) {
            int o = ob + r;
            float iv = gamma[o] * rsqrtf(rvar[o] + 1e-5f);
            inv[r] = iv; add[r] = beta[o] - rmean[o] * iv;
        }
#pragma unroll
        for (int j = 0; j < 4; j++) {
            int n_g = n0 + wn + j * 16 + col;
            int bb = n_g >> 12, hw = n_g & 4095;
            float* op = out + ((long)bb << 20) + hw;
#pragma unroll
            for (int r = 0; r < 4; r++) {
                float v = acc[i][j][r] * inv[r] + add[r];
                v = fmaxf(v, 0.f);
                op[(long)(ob + r) << 12] = v;
            }
        }
    }
}

// ---------------------------------------------------------------------------
extern "C" void kernel_launch(void* const* d_in, const int* in_sizes, int n_in,
                              void* d_out, int out_size, void* d_ws, size_t ws_size,
                              hipStream_t stream) {
    const float* x     = (const float*)d_in[0];
    const float* woff  = (const float*)d_in[1];
    const float* boff  = (const float*)d_in[2];
    const float* wmod  = (const float*)d_in[3];
    const float* bmod  = (const float*)d_in[4];
    const float* wreg  = (const float*)d_in[5];
    const float* gamma = (const float*)d_in[6];
    const float* beta  = (const float*)d_in[7];
    const float* rmean = (const float*)d_in[8];
    const float* rvar  = (const float*)d_in[9];
    float* out = (float*)d_out;

    char* ws = (char*)d_ws;
    // ws map:
    //   [0x000000, 0x03F000) wprep   fp32  258 KB
    //   [0x060000, 0x210000) offsum  fp32  1.77 MB (zeroed each call)
    //   [0x260000, 0x410000) offf    fp32  1.77 MB
    //   [0x410000, 0x531000) wregb   bf16  1.18 MB
    //   [0x540000, ...     ) samp    bf16  2304*NL*2 bytes (NL adaptive)
    float* wprep  = (float*)(ws);
    float* offsum = (float*)(ws + 0x60000u);
    float* offf   = (float*)(ws + 0x260000u);
    u16*   wregb  = (u16*)(ws + 0x410000u);
    u16*   samp   = (u16*)(ws + 0x540000u);

    // pick largest chunk that fits the workspace (ws_size constant per session)
    int NL = 16384;
    while (NL > 2048 && 0x540000ull + 2304ull * NL * 2ull > (unsigned long long)ws_size)
        NL >>= 1;
    int nchunk = 16384 / NL;

    zerok   <<<1728, 256, 0, stream>>>(offsum);
    kprep   <<<252,  256, 0, stream>>>(woff, wmod, wprep);
    kwreg   <<<2304, 256, 0, stream>>>(wreg, wregb);
    koffmask<<<256,  256, 0, stream>>>(x, wprep, offsum);
    kfin    <<<1728, 256, 0, stream>>>(offsum, boff, bmod, offf);
    for (int c = 0; c < nchunk; c++) {
        ksamp<<<dim3(NL / 64, 2),  256, 0, stream>>>(x, offf, samp, c * NL, NL);
        kgemm<<<dim3(NL / 128, 2), 256, 0, stream>>>(wregb, samp, gamma, beta,
                                                     rmean, rvar, out, c * NL, NL);
    }
}

// Round 6
// 341.474 us; speedup vs baseline: 2.7710x; 1.0639x over previous
//
#include <hip/hip_runtime.h>
#include <hip/hip_bf16.h>

typedef unsigned short u16;
typedef unsigned int   u32;
typedef short   bf16x8 __attribute__((ext_vector_type(8)));  // bf16 carried as i16
typedef float   f32x4  __attribute__((ext_vector_type(4)));

__device__ __forceinline__ u32 f2bf(float f) {
    u32 u = __builtin_bit_cast(u32, f);
    return (u + 0x7FFFu + ((u >> 16) & 1u)) >> 16;   // RNE
}

// ---------------------------------------------------------------------------
// Kernel 0a: repack conv weights (f32) -> fp32 wprep[r][28]
// r = c*9 + tap (2304 rows), cols 0..17 = w_off, 18..26 = w_mod, 27 = 0 pad.
// ---------------------------------------------------------------------------
__global__ void kprep(const float* __restrict__ woff, const float* __restrict__ wmod,
                      float* __restrict__ wprep) {
    int i = blockIdx.x * 256 + threadIdx.x;
    if (i >= 2304 * 28) return;
    int r = i / 28, oc = i - r * 28;
    float v = 0.f;
    if (oc < 18)      v = woff[oc * 2304 + r];
    else if (oc < 27) v = wmod[(oc - 18) * 2304 + r];
    wprep[i] = v;
}

// ---------------------------------------------------------------------------
// Kernel 0b: convert w_reg f32 -> bf16, layout [o][r] (r = c*9+tap), 589824 elts
// ---------------------------------------------------------------------------
__global__ void kwreg(const float* __restrict__ wreg, u16* __restrict__ wregb) {
    int i = blockIdx.x * 256 + threadIdx.x;      // 2304 blocks exact
    wregb[i] = (u16)f2bf(wreg[i]);
}

// ---------------------------------------------------------------------------
// Kernel 1: offset/mask conv. Block = (256-pixel band: 4 rows of one image,
// c-group g of 32 ch). Grid 512 = 2 blocks/CU (2 waves/SIMD for TLP).
// LDS x-band double-buffered, ONE barrier per channel. No atomics:
// partials to part[g][27][16384].
// ---------------------------------------------------------------------------
__global__ __launch_bounds__(256) void koffmask(const float* __restrict__ x,
                                                const float* __restrict__ wprep,
                                                float* __restrict__ part) {
    __shared__ float xs[2][6 * 64];              // rows h0-1 .. h0+4, dbuf
    int tid = threadIdx.x;
    int nb = blockIdx.x >> 3, g = blockIdx.x & 7;
    int n = nb * 256 + tid;
    int b = nb >> 4;
    int h0 = (nb & 15) << 2;                     // first row of the band
    int lr = tid >> 6, w = tid & 63;
    int h = h0 + lr;

    float vy[3], vx[3]; int xcc[3];
#pragma unroll
    for (int k = 0; k < 3; k++) {
        int y = h - 1 + k;
        vy[k] = (y >= 0 && y < 64) ? 1.f : 0.f;
        int xx = w - 1 + k;
        vx[k] = (xx >= 0 && xx < 64) ? 1.f : 0.f;
        xcc[k] = min(max(xx, 0), 63);
    }
    float valid[9];
#pragma unroll
    for (int t = 0; t < 9; t++) valid[t] = vy[t / 3] * vx[t % 3];

    // staging: element i -> row i>>6 (global y = h0-1+(i>>6), clamped; the
    // valid mask zeroes out-of-range rows), col i&63
    const float* xb = x + (long)(b * 256 + g * 32) * 4096;
    int i0 = tid, i1 = tid + 256;
    int yc0 = min(max(h0 - 1 + (i0 >> 6), 0), 63);
    int yc1 = min(max(h0 - 1 + (i1 >> 6), 0), 63);
    long a0 = (long)yc0 * 64 + (i0 & 63);
    long a1 = (long)yc1 * 64 + (i1 & 63);
    bool has1 = tid < 128;

    float acc[28];
#pragma unroll
    for (int j = 0; j < 28; j++) acc[j] = 0.f;

    // prime buffer 0 with channel 0
    xs[0][i0] = xb[a0];
    if (has1) xs[0][i1] = xb[a1];
    __syncthreads();

    const float4* wp = (const float4*)wprep;
    for (int c = 0; c < 32; c++) {
        int cur = c & 1;
        float p0 = 0.f, p1 = 0.f;
        if (c < 31) {                            // prefetch channel c+1
            p0 = xb[(c + 1) * 4096 + a0];
            if (has1) p1 = xb[(c + 1) * 4096 + a1];
        }
        int r0 = (g * 32 + c) * 9;
#pragma unroll
        for (int t = 0; t < 9; t++) {
            float xv = xs[cur][(lr + t / 3) * 64 + xcc[t % 3]] * valid[t];
#pragma unroll
            for (int j = 0; j < 7; j++) {
                float4 wv = wp[(r0 + t) * 7 + j];
                acc[j * 4 + 0] += xv * wv.x;
                acc[j * 4 + 1] += xv * wv.y;
                acc[j * 4 + 2] += xv * wv.z;
                acc[j * 4 + 3] += xv * wv.w;
            }
        }
        xs[cur ^ 1][i0] = p0;                    // write OTHER buffer
        if (has1) xs[cur ^ 1][i1] = p1;
        __syncthreads();                         // one barrier per channel
    }
#pragma unroll
    for (int oc = 0; oc < 27; oc++) part[((g * 27 + oc) << 14) + n] = acc[oc];
}

// ---------------------------------------------------------------------------
// Kernel 1b: reduce 8 partials + bias (+2*sigmoid for mask) -> off_final
// off_final[3k+0]=dy_k, [3k+1]=dx_k, [3k+2]=mask_k  (each [16384] fp32)
// ---------------------------------------------------------------------------
__global__ void kfin(const float* __restrict__ part, const float* __restrict__ boff,
                     const float* __restrict__ bmod, float* __restrict__ offf) {
    int i = blockIdx.x * 256 + threadIdx.x;     // 27 * 16384 exact
    int oc = i >> 14, n = i & 16383;
    float s = 0.f;
#pragma unroll
    for (int g = 0; g < 8; g++) s += part[((g * 27 + oc) << 14) + n];
    int ch; float v;
    if (oc < 18) {
        v = s + boff[oc];
        ch = 3 * (oc >> 1) + (oc & 1);          // even ch -> dy, odd -> dx
    } else {
        float t = s + bmod[oc - 18];
        v = 2.f / (1.f + __expf(-t));
        ch = 3 * (oc - 18) + 2;
    }
    offf[(ch << 14) + n] = v;
}

// ---------------------------------------------------------------------------
// Kernel 2: deformable bilinear sampling for one NL-pixel chunk ->
// pre-fragmented samp[rb][nloc][8] bf16, rb = r>>3, r = c*9+k.
// grid = dim3(NL/64, 2), block 256 (64 pixels x 4 c-groups of 32).
// ---------------------------------------------------------------------------
__global__ __launch_bounds__(256) void ksamp(const float* __restrict__ x,
                                             const float* __restrict__ offf,
                                             u16* __restrict__ samp,
                                             int n0base, int NL) {
    int nl = threadIdx.x & 63, cg = threadIdx.x >> 6;
    int nb = blockIdx.x;
    int cq = (blockIdx.y << 2) | cg;            // 0..7, 32 channels each
    int nloc = nb * 64 + nl;                    // 0..NL-1
    int n = n0base + nloc;
    int b = n >> 12, hw = n & 4095, h = hw >> 6, w = hw & 63;

    int   o00[9], o01[9], o10[9], o11[9];
    float w00[9], w01[9], w10[9], w11[9];
#pragma unroll
    for (int k = 0; k < 9; k++) {
        float dy = offf[((3 * k + 0) << 14) + n];
        float dx = offf[((3 * k + 1) << 14) + n];
        float m  = offf[((3 * k + 2) << 14) + n];
        float py = (float)(h - 1 + (k / 3)) + dy;
        float px = (float)(w - 1 + (k % 3)) + dx;
        float y0f = floorf(py), x0f = floorf(px);
        float wy = py - y0f, wx = px - x0f;
        int iy0 = (int)y0f, ix0 = (int)x0f;
        int iy1 = iy0 + 1, ix1 = ix0 + 1;
        bool vy0 = (unsigned)iy0 < 64u, vy1 = (unsigned)iy1 < 64u;
        bool vx0 = (unsigned)ix0 < 64u, vx1 = (unsigned)ix1 < 64u;
        int cy0 = min(max(iy0, 0), 63), cy1 = min(max(iy1, 0), 63);
        int cx0 = min(max(ix0, 0), 63), cx1 = min(max(ix1, 0), 63);
        o00[k] = cy0 * 64 + cx0; o01[k] = cy0 * 64 + cx1;
        o10[k] = cy1 * 64 + cx0; o11[k] = cy1 * 64 + cx1;
        float a = 1.f - wy, bbw = 1.f - wx;
        w00[k] = (vy0 && vx0) ? a  * bbw * m : 0.f;
        w01[k] = (vy0 && vx1) ? a  * wx  * m : 0.f;
        w10[k] = (vy1 && vx0) ? wy * bbw * m : 0.f;
        w11[k] = (vy1 && vx1) ? wy * wx  * m : 0.f;
    }

    const float* xb = x + (long)(b * 256 + cq * 32) * 4096;
    u32 words[36];
    for (int c8 = 0; c8 < 4; c8++) {
        const float* xc8 = xb + c8 * 8 * 4096;
#pragma unroll
        for (int cc = 0; cc < 8; cc++) {
            const float* xc = xc8 + cc * 4096;
#pragma unroll
            for (int k = 0; k < 9; k++) {
                float v = w00[k] * xc[o00[k]] + w01[k] * xc[o01[k]] +
                          w10[k] * xc[o10[k]] + w11[k] * xc[o11[k]];
                int e = cc * 9 + k;
                u32 bv = f2bf(v);
                if (e & 1) words[e >> 1] |= bv << 16;
                else       words[e >> 1]  = bv;
            }
        }
        int rb0 = cq * 36 + c8 * 9;
#pragma unroll
        for (int o = 0; o < 9; o++) {
            uint4 pk = make_uint4(words[o * 4 + 0], words[o * 4 + 1],
                                  words[o * 4 + 2], words[o * 4 + 3]);
            *(uint4*)(samp + ((long)(rb0 + o) * NL + nloc) * 8) = pk;
        }
    }
}

// ---------------------------------------------------------------------------
// Kernel 3: GEMM for one NL-pixel chunk. Tile 128(o) x 64(n), BK=64.
// grid = dim3(NL/64, 2) -> 512 blocks (2 blocks/CU). 4 waves, each 64o x 32n.
// out[o][n] = relu(BN( sum_r wregb[o][r] * samp[r][nloc] ))
// ---------------------------------------------------------------------------
__global__ __launch_bounds__(256) void kgemm(const u16* __restrict__ wregb,
                                             const u16* __restrict__ samp,
                                             const float* __restrict__ gamma,
                                             const float* __restrict__ beta,
                                             const float* __restrict__ rmean,
                                             const float* __restrict__ rvar,
                                             float* __restrict__ out,
                                             int n0base, int NL) {
    __shared__ u16 Al[128 * 72];   // 128 o-rows, 64 k + 8 pad
    __shared__ u16 Bl[64 * 72];    // 64 n-rows, 64 k + 8 pad
    int tid = threadIdx.x;
    int mt = blockIdx.y, ntl = blockIdx.x;
    int o0 = mt * 128;
    int nloc0 = ntl * 64;
    int n0 = n0base + nloc0;
    int lane = tid & 63, wv = tid >> 6;
    int wo = (wv >> 1) * 64, wn = (wv & 1) * 32;
    int col = lane & 15, quad = lane >> 4;

    f32x4 acc[4][2];
#pragma unroll
    for (int i = 0; i < 4; i++)
#pragma unroll
        for (int j = 0; j < 2; j++) acc[i][j] = (f32x4){0.f, 0.f, 0.f, 0.f};

    for (int kt = 0; kt < 36; kt++) {
        int r0 = kt * 64;
        // stage A: 128 rows x 8 x 16B -> 4 loads/thread
#pragma unroll
        for (int i = 0; i < 4; i++) {
            int cidx = tid + i * 256;
            int o = cidx >> 3, qq = cidx & 7;
            *(uint4*)&Al[o * 72 + qq * 8] =
                *(const uint4*)(wregb + (long)(o0 + o) * 2304 + r0 + qq * 8);
        }
        // stage B: 8 rb-rows x 64 n -> 2 loads/thread, coalesced 16B/lane
        int rb0 = r0 >> 3;
#pragma unroll
        for (int i = 0; i < 2; i++) {
            int cidx = tid + i * 256;
            int rbl = cidx >> 6, nl2 = cidx & 63;
            *(uint4*)&Bl[nl2 * 72 + rbl * 8] =
                *(const uint4*)(samp + ((long)(rb0 + rbl) * NL + nloc0 + nl2) * 8);
        }
        __syncthreads();
#pragma unroll
        for (int ks = 0; ks < 2; ks++) {
            bf16x8 af[4], bfr[2];
#pragma unroll
            for (int i = 0; i < 4; i++)
                af[i] = *(const bf16x8*)&Al[(wo + i * 16 + col) * 72 + ks * 32 + quad * 8];
#pragma unroll
            for (int j = 0; j < 2; j++)
                bfr[j] = *(const bf16x8*)&Bl[(wn + j * 16 + col) * 72 + ks * 32 + quad * 8];
#pragma unroll
            for (int i = 0; i < 4; i++)
#pragma unroll
                for (int j = 0; j < 2; j++)
                    acc[i][j] = __builtin_amdgcn_mfma_f32_16x16x32_bf16(
                        af[i], bfr[j], acc[i][j], 0, 0, 0);
        }
        __syncthreads();
    }

    // epilogue: BN + ReLU, D layout: row(o) = quad*4+reg, col(n) = lane&15
#pragma unroll
    for (int i = 0; i < 4; i++) {
        int ob = o0 + wo + i * 16 + quad * 4;
        float inv[4], add[4];
#pragma unroll
        for (int r = 0; r < 4; r++) {
            int o = ob + r;
            float iv = gamma[o] * rsqrtf(rvar[o] + 1e-5f);
            inv[r] = iv; add[r] = beta[o] - rmean[o] * iv;
        }
#pragma unroll
        for (int j = 0; j < 2; j++) {
            int n_g = n0 + wn + j * 16 + col;
            int bb = n_g >> 12, hw = n_g & 4095;
            float* op = out + ((long)bb << 20) + hw;
#pragma unroll
            for (int r = 0; r < 4; r++) {
                float v = acc[i][j][r] * inv[r] + add[r];
                v = fmaxf(v, 0.f);
                op[(long)(ob + r) << 12] = v;
            }
        }
    }
}

// ---------------------------------------------------------------------------
extern "C" void kernel_launch(void* const* d_in, const int* in_sizes, int n_in,
                              void* d_out, int out_size, void* d_ws, size_t ws_size,
                              hipStream_t stream) {
    const float* x     = (const float*)d_in[0];
    const float* woff  = (const float*)d_in[1];
    const float* boff  = (const float*)d_in[2];
    const float* wmod  = (const float*)d_in[3];
    const float* bmod  = (const float*)d_in[4];
    const float* wreg  = (const float*)d_in[5];
    const float* gamma = (const float*)d_in[6];
    const float* beta  = (const float*)d_in[7];
    const float* rmean = (const float*)d_in[8];
    const float* rvar  = (const float*)d_in[9];
    float* out = (float*)d_out;

    char* ws = (char*)d_ws;
    // ws map:
    //   [0x0000000, 0x003F000) wprep  fp32  258 KB
    //   [0x0060000, 0x0E8C000) part   fp32  14.2 MB (8 groups x 27 x 16384)
    //   [0x0F00000, 0x10C0000) offf   fp32  1.77 MB
    //   [0x1100000, 0x1227000) wregb  bf16  1.18 MB
    //   [0x1300000, ...      ) samp   bf16  2304*NL*2 bytes (NL adaptive)
    float* wprep = (float*)(ws);
    float* part  = (float*)(ws + 0x60000u);
    float* offf  = (float*)(ws + 0xF00000u);
    u16*   wregb = (u16*)(ws + 0x1100000u);
    u16*   samp  = (u16*)(ws + 0x1300000u);

    // pick largest chunk that fits the workspace (ws_size constant per session)
    int NL = 16384;
    while (NL > 2048 && 0x1300000ull + 2304ull * NL * 2ull > (unsigned long long)ws_size)
        NL >>= 1;
    int nchunk = 16384 / NL;

    kprep   <<<252,  256, 0, stream>>>(woff, wmod, wprep);
    kwreg   <<<2304, 256, 0, stream>>>(wreg, wregb);
    koffmask<<<512,  256, 0, stream>>>(x, wprep, part);
    kfin    <<<1728, 256, 0, stream>>>(part, boff, bmod, offf);
    for (int c = 0; c < nchunk; c++) {
        ksamp<<<dim3(NL / 64, 2), 256, 0, stream>>>(x, offf, samp, c * NL, NL);
        kgemm<<<dim3(NL / 64, 2), 256, 0, stream>>>(wregb, samp, gamma, beta,
                                                    rmean, rvar, out, c * NL, NL);
    }
}

// Round 7
// 255.122 us; speedup vs baseline: 3.7089x; 1.3385x over previous
//
#include <hip/hip_runtime.h>
#include <hip/hip_bf16.h>

typedef unsigned short u16;
typedef unsigned int   u32;
typedef short   bf16x8 __attribute__((ext_vector_type(8)));  // bf16 carried as i16
typedef float   f32x4  __attribute__((ext_vector_type(4)));

__device__ __forceinline__ float bf2f(u16 u) {
    u32 t = ((u32)u) << 16;
    return __builtin_bit_cast(float, t);
}
__device__ __forceinline__ u32 f2bf(float f) {
    u32 u = __builtin_bit_cast(u32, f);
    return (u + 0x7FFFu + ((u >> 16) & 1u)) >> 16;   // RNE
}

// ---------------------------------------------------------------------------
// Kernel 0a: offset/mask conv weights -> hi/lo bf16 A[32][2304], r = t*256+c
// oc 0..17 = w_off, 18..26 = w_mod, 27..31 = 0.
// ---------------------------------------------------------------------------
__global__ void kprep(const float* __restrict__ woff, const float* __restrict__ wmod,
                      u16* __restrict__ ah, u16* __restrict__ al) {
    int i = blockIdx.x * 256 + threadIdx.x;      // 288 blocks -> 73728 exact
    if (i >= 32 * 2304) return;
    int oc = i / 2304, r = i - oc * 2304;
    int t = r >> 8, c = r & 255;
    float v = 0.f;
    if (oc < 18)      v = woff[oc * 2304 + c * 9 + t];
    else if (oc < 27) v = wmod[(oc - 18) * 2304 + c * 9 + t];
    u32 hb = f2bf(v);
    u32 lb = f2bf(v - bf2f((u16)hb));
    ah[i] = (u16)hb;
    al[i] = (u16)lb;
}

// ---------------------------------------------------------------------------
// Kernel 0b: convert w_reg f32 -> bf16, layout [o][r] (r = c*9+tap), 589824 elts
// ---------------------------------------------------------------------------
__global__ void kwreg(const float* __restrict__ wreg, u16* __restrict__ wregb) {
    int i = blockIdx.x * 256 + threadIdx.x;      // 2304 blocks exact
    wregb[i] = (u16)f2bf(wreg[i]);
}

// ---------------------------------------------------------------------------
// Kernel 1: offset/mask conv as MFMA GEMM, M=32 (27 live), N=16384, K=2304.
// K-order r = tap*256 + c; B = im2col of x built on the fly (tap shift =
// offset row read + border mask). hi/lo bf16 split on BOTH operands ->
// 3 MFMAs (hh + hl + lh), fp32-equivalent precision.
// Block: 256 thr, n-tile 32, grid 512 (2 blocks/CU). Fused bias+2sigmoid
// epilogue writes offf directly (kfin deleted).
// ---------------------------------------------------------------------------
__global__ __launch_bounds__(256) void koffg(const float* __restrict__ x,
                                             const u16* __restrict__ ah_g,
                                             const u16* __restrict__ al_g,
                                             const float* __restrict__ boff,
                                             const float* __restrict__ bmod,
                                             float* __restrict__ offf) {
    __shared__ u16 Ah[32 * 72], Al[32 * 72];     // 32 oc-rows, 64 k + 8 pad
    __shared__ u16 Bh[32 * 72], Bl[32 * 72];     // 32 n-rows,  64 k + 8 pad
    int tid = threadIdx.x;
    int n0 = blockIdx.x * 32;
    int b = n0 >> 12, h0 = (n0 & 4095) >> 6, w0 = n0 & 63;
    int lane = tid & 63, wv = tid >> 6;
    int mt = wv & 1, nt = wv >> 1;               // 2 m-tiles x 2 n-tiles of 16
    int col = lane & 15, quad = lane >> 4;

    // A staging: thread -> 8 u16 (16B) of one oc-row
    int aoc = tid >> 3, ak0 = (tid & 7) * 8;
    // B staging: thread -> pixel nl, 8 consecutive channels
    int nl = tid & 31, cl0 = (tid >> 5) * 8;

    f32x4 acc = (f32x4){0.f, 0.f, 0.f, 0.f};

    for (int kt = 0; kt < 36; kt++) {
        int t = kt >> 2, c0 = (kt & 3) << 6;
        int r0 = kt * 64;
        int dy = t / 3 - 1, dx = t % 3 - 1;
        // global loads first (overlap with pre-barrier)
        uint4 pah = *(const uint4*)(ah_g + aoc * 2304 + r0 + ak0);
        uint4 pal = *(const uint4*)(al_g + aoc * 2304 + r0 + ak0);
        int hp = h0 + dy, wp = w0 + nl + dx;
        bool vm = ((unsigned)hp < 64u) && ((unsigned)wp < 64u);
        int hc = min(max(hp, 0), 63), wc = min(max(wp, 0), 63);
        const float* xp = x + ((long)(b * 256 + c0 + cl0) << 12) + hc * 64 + wc;
        u32 whi[4], wlo[4];
#pragma unroll
        for (int i = 0; i < 8; i++) {
            float v = vm ? xp[(long)i << 12] : 0.f;
            u32 hb = f2bf(v);
            u32 lb = f2bf(v - bf2f((u16)hb));
            if (i & 1) { whi[i >> 1] |= hb << 16; wlo[i >> 1] |= lb << 16; }
            else       { whi[i >> 1]  = hb;       wlo[i >> 1]  = lb; }
        }
        __syncthreads();                         // prev-iter frag reads done
        *(uint4*)&Ah[aoc * 72 + ak0] = pah;
        *(uint4*)&Al[aoc * 72 + ak0] = pal;
        *(uint4*)&Bh[nl * 72 + cl0] = make_uint4(whi[0], whi[1], whi[2], whi[3]);
        *(uint4*)&Bl[nl * 72 + cl0] = make_uint4(wlo[0], wlo[1], wlo[2], wlo[3]);
        __syncthreads();
#pragma unroll
        for (int ks = 0; ks < 2; ks++) {
            int ko = ks * 32 + quad * 8;
            bf16x8 fah = *(const bf16x8*)&Ah[(mt * 16 + col) * 72 + ko];
            bf16x8 fal = *(const bf16x8*)&Al[(mt * 16 + col) * 72 + ko];
            bf16x8 fbh = *(const bf16x8*)&Bh[(nt * 16 + col) * 72 + ko];
            bf16x8 fbl = *(const bf16x8*)&Bl[(nt * 16 + col) * 72 + ko];
            acc = __builtin_amdgcn_mfma_f32_16x16x32_bf16(fah, fbh, acc, 0, 0, 0);
            acc = __builtin_amdgcn_mfma_f32_16x16x32_bf16(fah, fbl, acc, 0, 0, 0);
            acc = __builtin_amdgcn_mfma_f32_16x16x32_bf16(fal, fbh, acc, 0, 0, 0);
        }
    }

    // epilogue: D row(oc) = mt*16 + quad*4 + r, col(n) = nt*16 + (lane&15)
    int n = n0 + nt * 16 + col;
#pragma unroll
    for (int r = 0; r < 4; r++) {
        int oc = mt * 16 + quad * 4 + r;
        float s = acc[r];
        if (oc < 18) {
            int ch = 3 * (oc >> 1) + (oc & 1);   // even oc -> dy, odd -> dx
            offf[(ch << 14) + n] = s + boff[oc];
        } else if (oc < 27) {
            float tt = s + bmod[oc - 18];
            int ch = 3 * (oc - 18) + 2;
            offf[(ch << 14) + n] = 2.f / (1.f + __expf(-tt));
        }
    }
}

// ---------------------------------------------------------------------------
// Kernel 2: deformable bilinear sampling for one NL-pixel chunk ->
// pre-fragmented samp[rb][nloc][8] bf16, rb = r>>3, r = c*9+k.
// grid = dim3(NL/64, 2), block 256 (64 pixels x 4 c-groups of 32).
// ---------------------------------------------------------------------------
__global__ __launch_bounds__(256) void ksamp(const float* __restrict__ x,
                                             const float* __restrict__ offf,
                                             u16* __restrict__ samp,
                                             int n0base, int NL) {
    int nl = threadIdx.x & 63, cg = threadIdx.x >> 6;
    int nb = blockIdx.x;
    int cq = (blockIdx.y << 2) | cg;            // 0..7, 32 channels each
    int nloc = nb * 64 + nl;                    // 0..NL-1
    int n = n0base + nloc;
    int b = n >> 12, hw = n & 4095, h = hw >> 6, w = hw & 63;

    int   o00[9], o01[9], o10[9], o11[9];
    float w00[9], w01[9], w10[9], w11[9];
#pragma unroll
    for (int k = 0; k < 9; k++) {
        float dy = offf[((3 * k + 0) << 14) + n];
        float dx = offf[((3 * k + 1) << 14) + n];
        float m  = offf[((3 * k + 2) << 14) + n];
        float py = (float)(h - 1 + (k / 3)) + dy;
        float px = (float)(w - 1 + (k % 3)) + dx;
        float y0f = floorf(py), x0f = floorf(px);
        float wy = py - y0f, wx = px - x0f;
        int iy0 = (int)y0f, ix0 = (int)x0f;
        int iy1 = iy0 + 1, ix1 = ix0 + 1;
        bool vy0 = (unsigned)iy0 < 64u, vy1 = (unsigned)iy1 < 64u;
        bool vx0 = (unsigned)ix0 < 64u, vx1 = (unsigned)ix1 < 64u;
        int cy0 = min(max(iy0, 0), 63), cy1 = min(max(iy1, 0), 63);
        int cx0 = min(max(ix0, 0), 63), cx1 = min(max(ix1, 0), 63);
        o00[k] = cy0 * 64 + cx0; o01[k] = cy0 * 64 + cx1;
        o10[k] = cy1 * 64 + cx0; o11[k] = cy1 * 64 + cx1;
        float a = 1.f - wy, bbw = 1.f - wx;
        w00[k] = (vy0 && vx0) ? a  * bbw * m : 0.f;
        w01[k] = (vy0 && vx1) ? a  * wx  * m : 0.f;
        w10[k] = (vy1 && vx0) ? wy * bbw * m : 0.f;
        w11[k] = (vy1 && vx1) ? wy * wx  * m : 0.f;
    }

    const float* xb = x + (long)(b * 256 + cq * 32) * 4096;
    u32 words[36];
    for (int c8 = 0; c8 < 4; c8++) {
        const float* xc8 = xb + c8 * 8 * 4096;
#pragma unroll
        for (int cc = 0; cc < 8; cc++) {
            const float* xc = xc8 + cc * 4096;
#pragma unroll
            for (int k = 0; k < 9; k++) {
                float v = w00[k] * xc[o00[k]] + w01[k] * xc[o01[k]] +
                          w10[k] * xc[o10[k]] + w11[k] * xc[o11[k]];
                int e = cc * 9 + k;
                u32 bv = f2bf(v);
                if (e & 1) words[e >> 1] |= bv << 16;
                else       words[e >> 1]  = bv;
            }
        }
        int rb0 = cq * 36 + c8 * 9;
#pragma unroll
        for (int o = 0; o < 9; o++) {
            uint4 pk = make_uint4(words[o * 4 + 0], words[o * 4 + 1],
                                  words[o * 4 + 2], words[o * 4 + 3]);
            *(uint4*)(samp + ((long)(rb0 + o) * NL + nloc) * 8) = pk;
        }
    }
}

// ---------------------------------------------------------------------------
// Kernel 3: GEMM for one NL-pixel chunk. Tile 128(o) x 64(n), BK=64.
// grid = dim3(NL/64, 2) -> 512 blocks (2 blocks/CU). 4 waves, each 64o x 32n.
// out[o][n] = relu(BN( sum_r wregb[o][r] * samp[r][nloc] ))
// ---------------------------------------------------------------------------
__global__ __launch_bounds__(256) void kgemm(const u16* __restrict__ wregb,
                                             const u16* __restrict__ samp,
                                             const float* __restrict__ gamma,
                                             const float* __restrict__ beta,
                                             const float* __restrict__ rmean,
                                             const float* __restrict__ rvar,
                                             float* __restrict__ out,
                                             int n0base, int NL) {
    __shared__ u16 Al[128 * 72];   // 128 o-rows, 64 k + 8 pad
    __shared__ u16 Bl[64 * 72];    // 64 n-rows, 64 k + 8 pad
    int tid = threadIdx.x;
    int mt = blockIdx.y, ntl = blockIdx.x;
    int o0 = mt * 128;
    int nloc0 = ntl * 64;
    int n0 = n0base + nloc0;
    int lane = tid & 63, wv = tid >> 6;
    int wo = (wv >> 1) * 64, wn = (wv & 1) * 32;
    int col = lane & 15, quad = lane >> 4;

    f32x4 acc[4][2];
#pragma unroll
    for (int i = 0; i < 4; i++)
#pragma unroll
        for (int j = 0; j < 2; j++) acc[i][j] = (f32x4){0.f, 0.f, 0.f, 0.f};

    for (int kt = 0; kt < 36; kt++) {
        int r0 = kt * 64;
#pragma unroll
        for (int i = 0; i < 4; i++) {
            int cidx = tid + i * 256;
            int o = cidx >> 3, qq = cidx & 7;
            *(uint4*)&Al[o * 72 + qq * 8] =
                *(const uint4*)(wregb + (long)(o0 + o) * 2304 + r0 + qq * 8);
        }
        int rb0 = r0 >> 3;
#pragma unroll
        for (int i = 0; i < 2; i++) {
            int cidx = tid + i * 256;
            int rbl = cidx >> 6, nl2 = cidx & 63;
            *(uint4*)&Bl[nl2 * 72 + rbl * 8] =
                *(const uint4*)(samp + ((long)(rb0 + rbl) * NL + nloc0 + nl2) * 8);
        }
        __syncthreads();
#pragma unroll
        for (int ks = 0; ks < 2; ks++) {
            bf16x8 af[4], bfr[2];
#pragma unroll
            for (int i = 0; i < 4; i++)
                af[i] = *(const bf16x8*)&Al[(wo + i * 16 + col) * 72 + ks * 32 + quad * 8];
#pragma unroll
            for (int j = 0; j < 2; j++)
                bfr[j] = *(const bf16x8*)&Bl[(wn + j * 16 + col) * 72 + ks * 32 + quad * 8];
#pragma unroll
            for (int i = 0; i < 4; i++)
#pragma unroll
                for (int j = 0; j < 2; j++)
                    acc[i][j] = __builtin_amdgcn_mfma_f32_16x16x32_bf16(
                        af[i], bfr[j], acc[i][j], 0, 0, 0);
        }
        __syncthreads();
    }

    // epilogue: BN + ReLU, D layout: row(o) = quad*4+reg, col(n) = lane&15
#pragma unroll
    for (int i = 0; i < 4; i++) {
        int ob = o0 + wo + i * 16 + quad * 4;
        float inv[4], add[4];
#pragma unroll
        for (int r = 0; r < 4; r++) {
            int o = ob + r;
            float iv = gamma[o] * rsqrtf(rvar[o] + 1e-5f);
            inv[r] = iv; add[r] = beta[o] - rmean[o] * iv;
        }
#pragma unroll
        for (int j = 0; j < 2; j++) {
            int n_g = n0 + wn + j * 16 + col;
            int bb = n_g >> 12, hw = n_g & 4095;
            float* op = out + ((long)bb << 20) + hw;
#pragma unroll
            for (int r = 0; r < 4; r++) {
                float v = acc[i][j][r] * inv[r] + add[r];
                v = fmaxf(v, 0.f);
                op[(long)(ob + r) << 12] = v;
            }
        }
    }
}

// ---------------------------------------------------------------------------
extern "C" void kernel_launch(void* const* d_in, const int* in_sizes, int n_in,
                              void* d_out, int out_size, void* d_ws, size_t ws_size,
                              hipStream_t stream) {
    const float* x     = (const float*)d_in[0];
    const float* woff  = (const float*)d_in[1];
    const float* boff  = (const float*)d_in[2];
    const float* wmod  = (const float*)d_in[3];
    const float* bmod  = (const float*)d_in[4];
    const float* wreg  = (const float*)d_in[5];
    const float* gamma = (const float*)d_in[6];
    const float* beta  = (const float*)d_in[7];
    const float* rmean = (const float*)d_in[8];
    const float* rvar  = (const float*)d_in[9];
    float* out = (float*)d_out;

    char* ws = (char*)d_ws;
    // ws map:
    //   [0x000000, 0x024000) wph   bf16  144 KB (A hi)
    //   [0x040000, 0x064000) wpl   bf16  144 KB (A lo)
    //   [0x080000, 0x23C000) offf  fp32  1.77 MB
    //   [0x240000, 0x360000) wregb bf16  1.18 MB
    //   [0x400000, ...     ) samp  bf16  2304*NL*2 bytes (NL adaptive)
    u16*   wph   = (u16*)(ws);
    u16*   wpl   = (u16*)(ws + 0x40000u);
    float* offf  = (float*)(ws + 0x80000u);
    u16*   wregb = (u16*)(ws + 0x240000u);
    u16*   samp  = (u16*)(ws + 0x400000u);

    // pick largest chunk that fits the workspace (ws_size constant per session)
    int NL = 16384;
    while (NL > 2048 && 0x400000ull + 2304ull * NL * 2ull > (unsigned long long)ws_size)
        NL >>= 1;
    int nchunk = 16384 / NL;

    kprep<<<288,  256, 0, stream>>>(woff, wmod, wph, wpl);
    kwreg<<<2304, 256, 0, stream>>>(wreg, wregb);
    koffg<<<512,  256, 0, stream>>>(x, wph, wpl, boff, bmod, offf);
    for (int c = 0; c < nchunk; c++) {
        ksamp<<<dim3(NL / 64, 2), 256, 0, stream>>>(x, offf, samp, c * NL, NL);
        kgemm<<<dim3(NL / 64, 2), 256, 0, stream>>>(wregb, samp, gamma, beta,
                                                    rmean, rvar, out, c * NL, NL);
    }
}